// Round 6
// baseline (315.963 us; speedup 1.0000x reference)
//
#include <hip/hip_runtime.h>
#include <stdint.h>

#define B_ 4
#define N_ 2048
#define C_ 768
#define H_ 12
#define D_ 64
#define NTOK 8192   // B_*N_

typedef short bf16x8 __attribute__((ext_vector_type(8)));
typedef float f32x4 __attribute__((ext_vector_type(4)));
typedef float f32x16 __attribute__((ext_vector_type(16)));
typedef unsigned short ushort8 __attribute__((ext_vector_type(8)));
typedef unsigned short u16x4 __attribute__((ext_vector_type(4)));

__device__ __forceinline__ unsigned short f2bf(float f) {
  union { float f; unsigned u; } v; v.f = f;
  unsigned r = v.u + 0x7FFFu + ((v.u >> 16) & 1u);
  return (unsigned short)(r >> 16);
}

// async global->LDS, 16B per lane. lds base must be wave-uniform; HW adds lane*16.
__device__ __forceinline__ void load_lds16(const void* g, void* lds_base) {
  __builtin_amdgcn_global_load_lds(
      (const __attribute__((address_space(1))) unsigned int*)g,
      (__attribute__((address_space(3))) unsigned int*)(uint32_t)(uintptr_t)lds_base,
      16, 0, 0);
}

// pack 8 non-negative floats -> bf16x8 via v_perm, truncating (softmax ratio
// cancels the tiny downward bias)
__device__ __forceinline__ bf16x8 pack8t(const float* p) {
  union { unsigned u[4]; bf16x8 v; } r;
#pragma unroll
  for (int j=0;j<4;j++) {
    union { float f; unsigned u; } a, b;
    a.f = p[2*j]; b.f = p[2*j+1];
    r.u[j] = __builtin_amdgcn_perm(b.u, a.u, 0x07060302u);
  }
  return r.v;
}

// ---------------- fp32 -> bf16 conversion (6 tensors) + u-table (y==6) ----------------
// u[b,m] = exp2(-mask2[b,m]*invT*log2e): per-key softmax bias factored out of exp.
__global__ __launch_bounds__(256) void cvt6(
    const float* s0, const float* s1, const float* s2, const float* s3,
    const float* s4, const float* s5,
    unsigned short* d0, unsigned short* d1, unsigned short* d2,
    unsigned short* d3, unsigned short* d4, unsigned short* d5,
    const float* mask2, const float* temp, float* u,
    int n01, int n25)
{
  int y = blockIdx.y;
  int i = (blockIdx.x*256 + threadIdx.x)*8;
  if (y == 6) {
    if (i >= NTOK) return;
    const float nsc = -1.4426950408889634f / temp[0];
    float4 f0 = *(const float4*)(mask2+i);
    float4 f1 = *(const float4*)(mask2+i+4);
    float4 o0, o1;
    o0.x = __builtin_amdgcn_exp2f(f0.x*nsc); o0.y = __builtin_amdgcn_exp2f(f0.y*nsc);
    o0.z = __builtin_amdgcn_exp2f(f0.z*nsc); o0.w = __builtin_amdgcn_exp2f(f0.w*nsc);
    o1.x = __builtin_amdgcn_exp2f(f1.x*nsc); o1.y = __builtin_amdgcn_exp2f(f1.y*nsc);
    o1.z = __builtin_amdgcn_exp2f(f1.z*nsc); o1.w = __builtin_amdgcn_exp2f(f1.w*nsc);
    *(float4*)(u+i) = o0;
    *(float4*)(u+i+4) = o1;
    return;
  }
  const float* s = (y==0)?s0:(y==1)?s1:(y==2)?s2:(y==3)?s3:(y==4)?s4:s5;
  unsigned short* d = (y==0)?d0:(y==1)?d1:(y==2)?d2:(y==3)?d3:(y==4)?d4:d5;
  int n = (y<2) ? n01 : n25;
  if (i >= n) return;
  float4 f0 = *(const float4*)(s+i);
  float4 f1 = *(const float4*)(s+i+4);
  ushort8 o;
  o[0]=f2bf(f0.x); o[1]=f2bf(f0.y); o[2]=f2bf(f0.z); o[3]=f2bf(f0.w);
  o[4]=f2bf(f1.x); o[5]=f2bf(f1.y); o[6]=f2bf(f1.z); o[7]=f2bf(f1.w);
  *(ushort8*)(d+i) = o;
}

// ---------------- shared GEMM core (R4 version): BK=32, 16.5KB LDS ----------------
__device__ __forceinline__ void gemm_core(const unsigned short* A, const unsigned short* W,
                                          int rowBase, int colBase, f32x4 (&acc)[4][4],
                                          unsigned short* As, unsigned short* Bs)
{
  int tid = threadIdx.x, wave = tid>>6, lane = tid&63, quad = lane>>4, l16 = lane&15;
  int wm = wave>>1, wn = wave&1;
  for (int k0 = 0; k0 < 768; k0 += 32) {
    __syncthreads();
#pragma unroll
    for (int p = 0; p < 2; ++p) {
      int c = p*256 + wave*64 + lane;
      load_lds16(A + (size_t)(rowBase + (c>>2))*768 + k0 + (c&3)*8,
                 As + (size_t)(p*256 + wave*64)*8);
      load_lds16(W + (size_t)(colBase + (c>>2))*768 + k0 + (c&3)*8,
                 Bs + (size_t)(p*256 + wave*64)*8);
    }
    __syncthreads();
    bf16x8 af[4], bw[4];
#pragma unroll
    for (int i=0;i<4;i++) af[i] = *(const bf16x8*)(As + (wm*64 + i*16 + l16)*32 + quad*8);
#pragma unroll
    for (int j=0;j<4;j++) bw[j] = *(const bf16x8*)(Bs + (wn*64 + j*16 + l16)*32 + quad*8);
#pragma unroll
    for (int i=0;i<4;i++)
#pragma unroll
      for (int j=0;j<4;j++)
        acc[i][j] = __builtin_amdgcn_mfma_f32_16x16x32_bf16(af[i], bw[j], acc[i][j], 0,0,0);
  }
}

// ---------------- QKV projection ----------------
// Q output scaled by SCL=0.125*log2e (exp2 arg needs no fma in attn).
// V output: transposed+slot-permuted [B,H,D,N], PRE-MULTIPLIED by u[key]
// (per-key softmax bias folded into V -> attn's PV needs no bias at all).
__global__ __launch_bounds__(256) void qkv_gemm(
    const unsigned short* xb1, const unsigned short* xb2,
    const unsigned short* Wq, const unsigned short* Wk, const unsigned short* Wv,
    const float* bq, const float* bk, const float* bv, const float* u,
    unsigned short* Qb, unsigned short* Kb, unsigned short* Vt)
{
  __shared__ unsigned short As[128*32];
  __shared__ unsigned short Bs[128*32];
  int z = blockIdx.z;
  const unsigned short* A = (z==0) ? xb1 : xb2;
  const unsigned short* W = (z==0) ? Wq : (z==1) ? Wk : Wv;
  const float* bias       = (z==0) ? bq : (z==1) ? bk : bv;
  int rowBase = blockIdx.x*128, colBase = blockIdx.y*128;
  int tid = threadIdx.x, wave = tid>>6, lane = tid&63, quad = lane>>4, l16 = lane&15;
  int wm = wave>>1, wn = wave&1;
  f32x4 acc[4][4] = {};
  gemm_core(A, W, rowBase, colBase, acc, As, Bs);
  if (z == 2) {
    // V': transposed write [B,H,D,N] with key->slot permutation, scaled by u[key]
#pragma unroll
    for (int i=0;i<4;i++) {
      int m0 = rowBase + wm*64 + i*16 + quad*4;     // global token row (b*2048+n)
      float4 uv = *(const float4*)(u + m0);          // u for keys m0..m0+3
      int b = m0 >> 11, n0 = m0 & 2047;
      int slotbase = (n0 & ~63) | (i*16) | ((quad&1)<<3) | ((quad>>1)<<2);
#pragma unroll
      for (int j=0;j<4;j++) {
        int col = colBase + wn*64 + j*16 + l16;
        float bv_ = bias[col];
        int h = col >> 6, d = col & 63;
        u16x4 o;
        o[0] = f2bf((acc[i][j][0] + bv_) * uv.x);
        o[1] = f2bf((acc[i][j][1] + bv_) * uv.y);
        o[2] = f2bf((acc[i][j][2] + bv_) * uv.z);
        o[3] = f2bf((acc[i][j][3] + bv_) * uv.w);
        *(u16x4*)(Vt + (((size_t)b*H_ + h)*D_ + d)*(size_t)N_ + slotbase) = o;
      }
    }
  } else {
    unsigned short* out = (z==0) ? Qb : Kb;
    float qs = (z==0) ? 0.18033688011112042f : 1.0f;  // 0.125*log2e for Q
#pragma unroll
    for (int i=0;i<4;i++)
#pragma unroll
      for (int j=0;j<4;j++) {
        int col = colBase + wn*64 + j*16 + l16;
        float bv_ = bias[col];
        int h = col >> 6, d = col & 63;
#pragma unroll
        for (int r=0;r<4;r++) {
          int m = rowBase + wm*64 + i*16 + quad*4 + r;
          int b = m >> 11, n = m & 2047;
          out[(((size_t)b*H_ + h)*N_ + n)*D_ + d] = f2bf((acc[i][j][r] + bv_) * qs);
        }
      }
  }
}

// stage one 64-tile of K ([key][d]) and V'^T ([d][slot]) via pure async loads,
// with source-side XOR chunk swizzle for conflict-free b128 fragment reads.
// 128-thread block version: 4 p-iterations per 8KB tile.
__device__ __forceinline__ void attn_stage(const unsigned short* Kb, const unsigned short* Vtg,
                                           size_t bh, int kt, int tid, int wave,
                                           unsigned short* KsBuf, unsigned short* VsBuf)
{
#pragma unroll
  for (int p=0;p<4;p++) {
    int idx = p*128 + tid;
    int key = idx >> 3, c = idx & 7;
    load_lds16(Kb + (bh*N_ + (size_t)kt*64 + key)*D_ + (c ^ (key & 7))*8,
               KsBuf + (size_t)(p*128 + wave*64)*8);
  }
#pragma unroll
  for (int p=0;p<4;p++) {
    int idx = p*128 + tid;
    int d = idx >> 3, c = idx & 7;
    load_lds16(Vtg + (bh*D_ + d)*(size_t)N_ + kt*64 + (c ^ (d & 7))*8,
               VsBuf + (size_t)(p*128 + wave*64)*8);
  }
}

// ---------------- flash attention (R11: 64 q-rows/wave, 2-wave blocks) ----------------
// Each wave owns TWO 32-row q-groups; kf/V/us LDS fragments are shared across
// both groups' MFMAs -> LDS read traffic per FLOP halves (LDS port was ~80% busy).
__global__ __launch_bounds__(128) void attn_kernel(
    const unsigned short* Qb, const unsigned short* Kb, const unsigned short* Vtg,
    const float* u, unsigned short* Ob)
{
  __shared__ unsigned short Ks[2][64*64];  // [buf][key][d-chunk swizzled]
  __shared__ unsigned short Vs[2][64*64];  // [buf][d][slot-chunk swizzled]
  __shared__ float us[N_];                 // per-key weights for this b (8 KB)
  int bx = blockIdx.x;                     // 0..767
  int xcd = bx & 7, slot = bx >> 3;        // 96 slots per xcd
  int bh_i = xcd*6 + (slot >> 4);          // 0..47
  int qt = slot & 15;
  int b = bh_i / H_, h = bh_i - b*H_;
  int tid = threadIdx.x;                   // 0..127
  int wave = tid>>6, lane = tid&63;
  int l32 = lane & 31, hl = lane >> 5;
  size_t bh = (size_t)bh_i;
  int qrow0 = qt*128 + wave*64 + l32;      // group-0 row; group-1 = +32

  // copy u[b,:] into LDS (lgkmcnt path, decoupled from staging vmcnt)
#pragma unroll
  for (int r=0;r<4;r++) {
    int i = (r*128 + tid)*4;
    *(float4*)(us+i) = *(const float4*)(u + (size_t)b*N_ + i);
  }

  bf16x8 qf0[4], qf1[4];
  const unsigned short* Qp0 = Qb + (bh*N_ + qrow0)*D_;
#pragma unroll
  for (int i=0;i<4;i++) {
    qf0[i] = *(const bf16x8*)(Qp0 + i*16 + hl*8);
    qf1[i] = *(const bf16x8*)(Qp0 + 32*D_ + i*16 + hl*8);
  }

  float lrun0 = 0.f, lrun1 = 0.f;
  f32x16 oacc00 = {}, oacc01 = {};   // group0: d 0-31, d 32-63
  f32x16 oacc10 = {}, oacc11 = {};   // group1

  attn_stage(Kb, Vtg, bh, 0, tid, wave, Ks[0], Vs[0]);
  __syncthreads();   // also covers us writes

  for (int kt = 0; kt < N_/64; ++kt) {
    int cur = kt & 1;
    if (kt+1 < N_/64)
      attn_stage(Kb, Vtg, bh, kt+1, tid, wave, Ks[cur^1], Vs[cur^1]);
    const unsigned short* Kc = Ks[cur];
    const unsigned short* Vc = Vs[cur];
#pragma unroll
    for (int sub=0; sub<2; ++sub) {
      f32x16 sa0 = {}, sa1 = {};
#pragma unroll
      for (int i=0;i<4;i++) {
        int ch = (2*i + hl) ^ (l32 & 7);
        bf16x8 kf = *(const bf16x8*)(Kc + (sub*32 + l32)*64 + ch*8);  // shared
        sa0 = __builtin_amdgcn_mfma_f32_32x32x16_bf16(kf, qf0[i], sa0, 0,0,0);
        sa1 = __builtin_amdgcn_mfma_f32_32x32x16_bf16(kf, qf1[i], sa1, 0,0,0);
      }
      float pv0[16], pv1[16];
      float la0 = 0.f, la1 = 0.f;
#pragma unroll
      for (int g=0; g<4; ++g) {
        float4 uv = *(const float4*)(us + kt*64 + sub*32 + g*8 + hl*4);  // shared
        float a0 = __builtin_amdgcn_exp2f(sa0[g*4+0]);
        float a1 = __builtin_amdgcn_exp2f(sa0[g*4+1]);
        float a2 = __builtin_amdgcn_exp2f(sa0[g*4+2]);
        float a3 = __builtin_amdgcn_exp2f(sa0[g*4+3]);
        float b0 = __builtin_amdgcn_exp2f(sa1[g*4+0]);
        float b1 = __builtin_amdgcn_exp2f(sa1[g*4+1]);
        float b2 = __builtin_amdgcn_exp2f(sa1[g*4+2]);
        float b3 = __builtin_amdgcn_exp2f(sa1[g*4+3]);
        pv0[g*4+0]=a0; pv0[g*4+1]=a1; pv0[g*4+2]=a2; pv0[g*4+3]=a3;
        pv1[g*4+0]=b0; pv1[g*4+1]=b1; pv1[g*4+2]=b2; pv1[g*4+3]=b3;
        la0 += fmaf(a0, uv.x, fmaf(a1, uv.y, fmaf(a2, uv.z, a3*uv.w)));
        la1 += fmaf(b0, uv.x, fmaf(b1, uv.y, fmaf(b2, uv.z, b3*uv.w)));
      }
      lrun0 += la0; lrun1 += la1;
      bf16x8 pf00 = pack8t(pv0);
      bf16x8 pf01 = pack8t(pv0+8);
      bf16x8 pf10 = pack8t(pv1);
      bf16x8 pf11 = pack8t(pv1+8);
#pragma unroll
      for (int kc=0;kc<2;kc++) {
        int m = sub*2 + kc;
        int chv = (2*m + hl) ^ (l32 & 7);
        bf16x8 vlo = *(const bf16x8*)(Vc + l32*64 + chv*8);        // shared
        int chv1 = (2*m + hl) ^ ((32+l32) & 7);
        bf16x8 vhi = *(const bf16x8*)(Vc + (32+l32)*64 + chv1*8);  // shared
        bf16x8 p0 = kc ? pf01 : pf00;
        bf16x8 p1 = kc ? pf11 : pf10;
        oacc00 = __builtin_amdgcn_mfma_f32_32x32x16_bf16(vlo, p0, oacc00, 0,0,0);
        oacc01 = __builtin_amdgcn_mfma_f32_32x32x16_bf16(vhi, p0, oacc01, 0,0,0);
        oacc10 = __builtin_amdgcn_mfma_f32_32x32x16_bf16(vlo, p1, oacc10, 0,0,0);
        oacc11 = __builtin_amdgcn_mfma_f32_32x32x16_bf16(vhi, p1, oacc11, 0,0,0);
      }
    }
    __syncthreads();
  }

  lrun0 += __shfl_xor(lrun0, 32);
  lrun1 += __shfl_xor(lrun1, 32);
  float rinv0 = 1.0f / lrun0;
  float rinv1 = 1.0f / lrun1;
  size_t obase0 = ((size_t)b*N_ + qrow0)*C_ + h*D_;
  size_t obase1 = obase0 + (size_t)32*C_;
#pragma unroll
  for (int dh=0; dh<2; ++dh)
#pragma unroll
    for (int g=0; g<4; ++g) {
      int d = dh*32 + g*8 + hl*4;
      u16x4 o0, o1;
#pragma unroll
      for (int q=0;q<4;q++) {
        float v0 = (dh==0 ? oacc00[g*4+q] : oacc01[g*4+q]) * rinv0;
        float v1 = (dh==0 ? oacc10[g*4+q] : oacc11[g*4+q]) * rinv1;
        o0[q] = f2bf(v0);
        o1[q] = f2bf(v1);
      }
      *(u16x4*)(Ob + obase0 + d) = o0;
      *(u16x4*)(Ob + obase1 + d) = o1;
    }
}

// ---------------- output projection + residual fuse: Z = O@Wo^T + bo + 0.5*x1 (fp32) ----------------
__global__ __launch_bounds__(256) void out_gemm(
    const unsigned short* Ob, const unsigned short* Wo, const float* bo,
    const float* x1, float* Z)
{
  __shared__ unsigned short As[128*32];
  __shared__ unsigned short Bs[128*32];
  int rowBase = blockIdx.x*128, colBase = blockIdx.y*128;
  int tid = threadIdx.x, wave = tid>>6, lane = tid&63, quad = lane>>4, l16 = lane&15;
  int wm = wave>>1, wn = wave&1;
  f32x4 acc[4][4] = {};
  gemm_core(Ob, Wo, rowBase, colBase, acc, As, Bs);
#pragma unroll
  for (int i=0;i<4;i++)
#pragma unroll
    for (int j=0;j<4;j++) {
      int col = colBase + wn*64 + j*16 + l16;
      float bv_ = bo[col];
#pragma unroll
      for (int r=0;r<4;r++) {
        size_t m = rowBase + wm*64 + i*16 + quad*4 + r;
        Z[m*768 + col] = acc[i][j][r] + bv_ + 0.5f*x1[m*768 + col];
      }
    }
}

// ---------------- layernorm: one block per row ----------------
__global__ __launch_bounds__(256) void ln_kernel(const float* Z, const float* gam,
                                                 const float* bet, float* out)
{
  size_t row = blockIdx.x;
  int t = threadIdx.x;
  const float* z = Z + row*768;
  float v0 = z[t], v1 = z[t+256], v2 = z[t+512];
  float s = v0+v1+v2;
  float ss = v0*v0 + v1*v1 + v2*v2;
#pragma unroll
  for (int off=1; off<64; off<<=1) { s += __shfl_xor(s, off); ss += __shfl_xor(ss, off); }
  __shared__ float red[8];
  int wave = t>>6, lane = t&63;
  if (lane==0) { red[wave] = s; red[4+wave] = ss; }
  __syncthreads();
  float S = red[0]+red[1]+red[2]+red[3];
  float SS = red[4]+red[5]+red[6]+red[7];
  float mean = S * (1.0f/768.0f);
  float var = SS * (1.0f/768.0f) - mean*mean;
  float rstd = rsqrtf(var + 1e-5f);
  float* o = out + row*768;
  o[t]     = (v0-mean)*rstd*gam[t]     + bet[t];
  o[t+256] = (v1-mean)*rstd*gam[t+256] + bet[t+256];
  o[t+512] = (v2-mean)*rstd*gam[t+512] + bet[t+512];
}

extern "C" void kernel_launch(void* const* d_in, const int* in_sizes, int n_in,
                              void* d_out, int out_size, void* d_ws, size_t ws_size,
                              hipStream_t stream)
{
  const float* x1    = (const float*)d_in[0];
  const float* x2    = (const float*)d_in[1];
  const float* mask2 = (const float*)d_in[3];
  const float* Wq    = (const float*)d_in[4];
  const float* bq    = (const float*)d_in[5];
  const float* Wk    = (const float*)d_in[6];
  const float* bk    = (const float*)d_in[7];
  const float* Wv    = (const float*)d_in[8];
  const float* bv    = (const float*)d_in[9];
  const float* Wo    = (const float*)d_in[10];
  const float* bo    = (const float*)d_in[11];
  const float* temp  = (const float*)d_in[12];
  const float* gam   = (const float*)d_in[13];
  const float* bet   = (const float*)d_in[14];

  char* ws = (char*)d_ws;
  size_t off = 0;
  auto alloc = [&](size_t bytes) { void* p = ws + off; off += (bytes + 255) & ~255ull; return p; };
  const size_t XB = (size_t)NTOK * C_ * 2;   // 12582912
  const size_t WB = (size_t)C_ * C_ * 2;     // 1179648
  unsigned short* xb1 = (unsigned short*)alloc(XB);
  unsigned short* xb2 = (unsigned short*)alloc(XB);
  unsigned short* Wqb = (unsigned short*)alloc(WB);
  unsigned short* Wkb = (unsigned short*)alloc(WB);
  unsigned short* Wvb = (unsigned short*)alloc(WB);
  unsigned short* Wob = (unsigned short*)alloc(WB);
  unsigned short* Qb  = (unsigned short*)alloc(XB);
  unsigned short* Kb  = (unsigned short*)alloc(XB);
  unsigned short* Vt  = (unsigned short*)alloc(XB);  // V' directly in [B,H,D,N] slot-permuted
  unsigned short* Ob  = (unsigned short*)alloc(XB);
  float* u = (float*)alloc((size_t)NTOK * 4);        // per-key softmax weights
  // Z overlays xb1+xb2: both are dead after qkv_gemm, and Z is only written
  // by out_gemm, after attn.
  float* Z = (float*)xb1;   // 25165824 B overlays xb1+xb2

  cvt6<<<dim3(3072, 7), 256, 0, stream>>>(x1, x2, Wq, Wk, Wv, Wo,
                                          xb1, xb2, Wqb, Wkb, Wvb, Wob,
                                          mask2, temp, u,
                                          NTOK*C_, C_*C_);
  qkv_gemm<<<dim3(64, 6, 3), 256, 0, stream>>>(xb1, xb2, Wqb, Wkb, Wvb,
                                               bq, bk, bv, u, Qb, Kb, Vt);
  attn_kernel<<<dim3(768), 128, 0, stream>>>(Qb, Kb, Vt, u, Ob);
  out_gemm<<<dim3(64, 6), 256, 0, stream>>>(Ob, Wob, bo, x1, Z);
  ln_kernel<<<dim3(8192), 256, 0, stream>>>(Z, gam, bet, (float*)d_out);
}

// Round 7
// 311.787 us; speedup vs baseline: 1.0134x; 1.0134x over previous
//
#include <hip/hip_runtime.h>
#include <stdint.h>

#define B_ 4
#define N_ 2048
#define C_ 768
#define H_ 12
#define D_ 64
#define NTOK 8192   // B_*N_

typedef short bf16x8 __attribute__((ext_vector_type(8)));
typedef float f32x4 __attribute__((ext_vector_type(4)));
typedef float f32x16 __attribute__((ext_vector_type(16)));
typedef unsigned short ushort8 __attribute__((ext_vector_type(8)));
typedef unsigned short u16x4 __attribute__((ext_vector_type(4)));

__device__ __forceinline__ unsigned short f2bf(float f) {
  union { float f; unsigned u; } v; v.f = f;
  unsigned r = v.u + 0x7FFFu + ((v.u >> 16) & 1u);
  return (unsigned short)(r >> 16);
}

// async global->LDS, 16B per lane. lds base must be wave-uniform; HW adds lane*16.
__device__ __forceinline__ void load_lds16(const void* g, void* lds_base) {
  __builtin_amdgcn_global_load_lds(
      (const __attribute__((address_space(1))) unsigned int*)g,
      (__attribute__((address_space(3))) unsigned int*)(uint32_t)(uintptr_t)lds_base,
      16, 0, 0);
}

// pack 8 non-negative floats -> bf16x8 via v_perm, truncating (softmax ratio
// cancels the tiny downward bias)
__device__ __forceinline__ bf16x8 pack8t(const float* p) {
  union { unsigned u[4]; bf16x8 v; } r;
#pragma unroll
  for (int j=0;j<4;j++) {
    union { float f; unsigned u; } a, b;
    a.f = p[2*j]; b.f = p[2*j+1];
    r.u[j] = __builtin_amdgcn_perm(b.u, a.u, 0x07060302u);
  }
  return r.v;
}

// ---------------- fp32 -> bf16 conversion (6 tensors) + u-table (y==6) ----------------
// u[b,m] = exp2(-mask2[b,m]*invT*log2e): per-key softmax bias factored out of exp.
__global__ __launch_bounds__(256) void cvt6(
    const float* s0, const float* s1, const float* s2, const float* s3,
    const float* s4, const float* s5,
    unsigned short* d0, unsigned short* d1, unsigned short* d2,
    unsigned short* d3, unsigned short* d4, unsigned short* d5,
    const float* mask2, const float* temp, float* u,
    int n01, int n25)
{
  int y = blockIdx.y;
  int i = (blockIdx.x*256 + threadIdx.x)*8;
  if (y == 6) {
    if (i >= NTOK) return;
    const float nsc = -1.4426950408889634f / temp[0];
    float4 f0 = *(const float4*)(mask2+i);
    float4 f1 = *(const float4*)(mask2+i+4);
    float4 o0, o1;
    o0.x = __builtin_amdgcn_exp2f(f0.x*nsc); o0.y = __builtin_amdgcn_exp2f(f0.y*nsc);
    o0.z = __builtin_amdgcn_exp2f(f0.z*nsc); o0.w = __builtin_amdgcn_exp2f(f0.w*nsc);
    o1.x = __builtin_amdgcn_exp2f(f1.x*nsc); o1.y = __builtin_amdgcn_exp2f(f1.y*nsc);
    o1.z = __builtin_amdgcn_exp2f(f1.z*nsc); o1.w = __builtin_amdgcn_exp2f(f1.w*nsc);
    *(float4*)(u+i) = o0;
    *(float4*)(u+i+4) = o1;
    return;
  }
  const float* s = (y==0)?s0:(y==1)?s1:(y==2)?s2:(y==3)?s3:(y==4)?s4:s5;
  unsigned short* d = (y==0)?d0:(y==1)?d1:(y==2)?d2:(y==3)?d3:(y==4)?d4:d5;
  int n = (y<2) ? n01 : n25;
  if (i >= n) return;
  float4 f0 = *(const float4*)(s+i);
  float4 f1 = *(const float4*)(s+i+4);
  ushort8 o;
  o[0]=f2bf(f0.x); o[1]=f2bf(f0.y); o[2]=f2bf(f0.z); o[3]=f2bf(f0.w);
  o[4]=f2bf(f1.x); o[5]=f2bf(f1.y); o[6]=f2bf(f1.z); o[7]=f2bf(f1.w);
  *(ushort8*)(d+i) = o;
}

// ---------------- shared GEMM core (R4 version): BK=32, 16.5KB LDS ----------------
__device__ __forceinline__ void gemm_core(const unsigned short* A, const unsigned short* W,
                                          int rowBase, int colBase, f32x4 (&acc)[4][4],
                                          unsigned short* As, unsigned short* Bs)
{
  int tid = threadIdx.x, wave = tid>>6, lane = tid&63, quad = lane>>4, l16 = lane&15;
  int wm = wave>>1, wn = wave&1;
  for (int k0 = 0; k0 < 768; k0 += 32) {
    __syncthreads();
#pragma unroll
    for (int p = 0; p < 2; ++p) {
      int c = p*256 + wave*64 + lane;
      load_lds16(A + (size_t)(rowBase + (c>>2))*768 + k0 + (c&3)*8,
                 As + (size_t)(p*256 + wave*64)*8);
      load_lds16(W + (size_t)(colBase + (c>>2))*768 + k0 + (c&3)*8,
                 Bs + (size_t)(p*256 + wave*64)*8);
    }
    __syncthreads();
    bf16x8 af[4], bw[4];
#pragma unroll
    for (int i=0;i<4;i++) af[i] = *(const bf16x8*)(As + (wm*64 + i*16 + l16)*32 + quad*8);
#pragma unroll
    for (int j=0;j<4;j++) bw[j] = *(const bf16x8*)(Bs + (wn*64 + j*16 + l16)*32 + quad*8);
#pragma unroll
    for (int i=0;i<4;i++)
#pragma unroll
      for (int j=0;j<4;j++)
        acc[i][j] = __builtin_amdgcn_mfma_f32_16x16x32_bf16(af[i], bw[j], acc[i][j], 0,0,0);
  }
}

// ---------------- QKV projection ----------------
// Q output scaled by SCL=0.125*log2e (exp2 arg needs no fma in attn).
// V output: transposed+slot-permuted [B,H,D,N], PRE-MULTIPLIED by u[key]
// (per-key softmax bias folded into V -> attn's PV needs no bias at all).
__global__ __launch_bounds__(256) void qkv_gemm(
    const unsigned short* xb1, const unsigned short* xb2,
    const unsigned short* Wq, const unsigned short* Wk, const unsigned short* Wv,
    const float* bq, const float* bk, const float* bv, const float* u,
    unsigned short* Qb, unsigned short* Kb, unsigned short* Vt)
{
  __shared__ unsigned short As[128*32];
  __shared__ unsigned short Bs[128*32];
  int z = blockIdx.z;
  const unsigned short* A = (z==0) ? xb1 : xb2;
  const unsigned short* W = (z==0) ? Wq : (z==1) ? Wk : Wv;
  const float* bias       = (z==0) ? bq : (z==1) ? bk : bv;
  int rowBase = blockIdx.x*128, colBase = blockIdx.y*128;
  int tid = threadIdx.x, wave = tid>>6, lane = tid&63, quad = lane>>4, l16 = lane&15;
  int wm = wave>>1, wn = wave&1;
  f32x4 acc[4][4] = {};
  gemm_core(A, W, rowBase, colBase, acc, As, Bs);
  if (z == 2) {
    // V': transposed write [B,H,D,N] with key->slot permutation, scaled by u[key]
#pragma unroll
    for (int i=0;i<4;i++) {
      int m0 = rowBase + wm*64 + i*16 + quad*4;     // global token row (b*2048+n)
      float4 uv = *(const float4*)(u + m0);          // u for keys m0..m0+3
      int b = m0 >> 11, n0 = m0 & 2047;
      int slotbase = (n0 & ~63) | (i*16) | ((quad&1)<<3) | ((quad>>1)<<2);
#pragma unroll
      for (int j=0;j<4;j++) {
        int col = colBase + wn*64 + j*16 + l16;
        float bv_ = bias[col];
        int h = col >> 6, d = col & 63;
        u16x4 o;
        o[0] = f2bf((acc[i][j][0] + bv_) * uv.x);
        o[1] = f2bf((acc[i][j][1] + bv_) * uv.y);
        o[2] = f2bf((acc[i][j][2] + bv_) * uv.z);
        o[3] = f2bf((acc[i][j][3] + bv_) * uv.w);
        *(u16x4*)(Vt + (((size_t)b*H_ + h)*D_ + d)*(size_t)N_ + slotbase) = o;
      }
    }
  } else {
    unsigned short* out = (z==0) ? Qb : Kb;
    float qs = (z==0) ? 0.18033688011112042f : 1.0f;  // 0.125*log2e for Q
#pragma unroll
    for (int i=0;i<4;i++)
#pragma unroll
      for (int j=0;j<4;j++) {
        int col = colBase + wn*64 + j*16 + l16;
        float bv_ = bias[col];
        int h = col >> 6, d = col & 63;
#pragma unroll
        for (int r=0;r<4;r++) {
          int m = rowBase + wm*64 + i*16 + quad*4 + r;
          int b = m >> 11, n = m & 2047;
          out[(((size_t)b*H_ + h)*N_ + n)*D_ + d] = f2bf((acc[i][j][r] + bv_) * qs);
        }
      }
  }
}

// stage one 64-tile of K ([key][d]) and V'^T ([d][slot]) via pure async loads,
// with source-side XOR chunk swizzle for conflict-free b128 fragment reads.
// 256-thread block: 2 p-iterations per 8KB tile.
__device__ __forceinline__ void attn_stage(const unsigned short* Kb, const unsigned short* Vtg,
                                           size_t bh, int kt, int tid, int wave,
                                           unsigned short* KsBuf, unsigned short* VsBuf)
{
#pragma unroll
  for (int p=0;p<2;p++) {
    int idx = p*256 + tid;
    int key = idx >> 3, c = idx & 7;
    load_lds16(Kb + (bh*N_ + (size_t)kt*64 + key)*D_ + (c ^ (key & 7))*8,
               KsBuf + (size_t)(p*256 + wave*64)*8);
  }
#pragma unroll
  for (int p=0;p<2;p++) {
    int idx = p*256 + tid;
    int d = idx >> 3, c = idx & 7;
    load_lds16(Vtg + (bh*D_ + d)*(size_t)N_ + kt*64 + (c ^ (d & 7))*8,
               VsBuf + (size_t)(p*256 + wave*64)*8);
  }
}

// ---------------- flash attention (R12: 4 waves x 64 q-rows = 256-row tile) ----------------
// Each wave owns TWO 32-row q-groups; kf/V/us LDS fragments are shared across
// both groups' MFMAs -> LDS read traffic per FLOP halves vs the 32-row/wave
// version, while keeping 4-wave blocks (R6's 2-wave blocks collapsed occupancy).
__global__ __launch_bounds__(256) void attn_kernel(
    const unsigned short* Qb, const unsigned short* Kb, const unsigned short* Vtg,
    const float* u, unsigned short* Ob)
{
  __shared__ unsigned short Ks[2][64*64];  // [buf][key][d-chunk swizzled]
  __shared__ unsigned short Vs[2][64*64];  // [buf][d][slot-chunk swizzled]
  __shared__ float us[N_];                 // per-key weights for this b (8 KB)
  int bx = blockIdx.x;                     // 0..383
  int xcd = bx & 7, slot = bx >> 3;        // 48 slots per xcd
  int bh_i = xcd*6 + (slot >> 3);          // 0..47
  int qt = slot & 7;                       // 8 q-tiles of 256 rows
  int b = bh_i / H_, h = bh_i - b*H_;
  int tid = threadIdx.x;                   // 0..255
  int wave = tid>>6, lane = tid&63;
  int l32 = lane & 31, hl = lane >> 5;
  size_t bh = (size_t)bh_i;
  int qrow0 = qt*256 + wave*64 + l32;      // group-0 row; group-1 = +32

  // copy u[b,:] into LDS (lgkmcnt path, decoupled from staging vmcnt)
#pragma unroll
  for (int r=0;r<2;r++) {
    int i = (r*256 + tid)*4;
    *(float4*)(us+i) = *(const float4*)(u + (size_t)b*N_ + i);
  }

  bf16x8 qf0[4], qf1[4];
  const unsigned short* Qp0 = Qb + (bh*N_ + qrow0)*D_;
#pragma unroll
  for (int i=0;i<4;i++) {
    qf0[i] = *(const bf16x8*)(Qp0 + i*16 + hl*8);
    qf1[i] = *(const bf16x8*)(Qp0 + 32*D_ + i*16 + hl*8);
  }

  float lrun0 = 0.f, lrun1 = 0.f;
  f32x16 oacc00 = {}, oacc01 = {};   // group0: d 0-31, d 32-63
  f32x16 oacc10 = {}, oacc11 = {};   // group1

  attn_stage(Kb, Vtg, bh, 0, tid, wave, Ks[0], Vs[0]);
  __syncthreads();   // also covers us writes

  for (int kt = 0; kt < N_/64; ++kt) {
    int cur = kt & 1;
    if (kt+1 < N_/64)
      attn_stage(Kb, Vtg, bh, kt+1, tid, wave, Ks[cur^1], Vs[cur^1]);
    const unsigned short* Kc = Ks[cur];
    const unsigned short* Vc = Vs[cur];
#pragma unroll
    for (int sub=0; sub<2; ++sub) {
      f32x16 sa0 = {}, sa1 = {};
#pragma unroll
      for (int i=0;i<4;i++) {
        int ch = (2*i + hl) ^ (l32 & 7);
        bf16x8 kf = *(const bf16x8*)(Kc + (sub*32 + l32)*64 + ch*8);  // shared
        sa0 = __builtin_amdgcn_mfma_f32_32x32x16_bf16(kf, qf0[i], sa0, 0,0,0);
        sa1 = __builtin_amdgcn_mfma_f32_32x32x16_bf16(kf, qf1[i], sa1, 0,0,0);
      }
      float pv0[16], pv1[16];
      float la0 = 0.f, la1 = 0.f;
#pragma unroll
      for (int g=0; g<4; ++g) {
        float4 uv = *(const float4*)(us + kt*64 + sub*32 + g*8 + hl*4);  // broadcast
        float a0 = __builtin_amdgcn_exp2f(sa0[g*4+0]);
        float a1 = __builtin_amdgcn_exp2f(sa0[g*4+1]);
        float a2 = __builtin_amdgcn_exp2f(sa0[g*4+2]);
        float a3 = __builtin_amdgcn_exp2f(sa0[g*4+3]);
        float b0 = __builtin_amdgcn_exp2f(sa1[g*4+0]);
        float b1 = __builtin_amdgcn_exp2f(sa1[g*4+1]);
        float b2 = __builtin_amdgcn_exp2f(sa1[g*4+2]);
        float b3 = __builtin_amdgcn_exp2f(sa1[g*4+3]);
        pv0[g*4+0]=a0; pv0[g*4+1]=a1; pv0[g*4+2]=a2; pv0[g*4+3]=a3;
        pv1[g*4+0]=b0; pv1[g*4+1]=b1; pv1[g*4+2]=b2; pv1[g*4+3]=b3;
        la0 += fmaf(a0, uv.x, fmaf(a1, uv.y, fmaf(a2, uv.z, a3*uv.w)));
        la1 += fmaf(b0, uv.x, fmaf(b1, uv.y, fmaf(b2, uv.z, b3*uv.w)));
      }
      lrun0 += la0; lrun1 += la1;
      bf16x8 pf00 = pack8t(pv0);
      bf16x8 pf01 = pack8t(pv0+8);
      bf16x8 pf10 = pack8t(pv1);
      bf16x8 pf11 = pack8t(pv1+8);
#pragma unroll
      for (int kc=0;kc<2;kc++) {
        int m = sub*2 + kc;
        int chv = (2*m + hl) ^ (l32 & 7);
        bf16x8 vlo = *(const bf16x8*)(Vc + l32*64 + chv*8);        // shared
        int chv1 = (2*m + hl) ^ ((32+l32) & 7);
        bf16x8 vhi = *(const bf16x8*)(Vc + (32+l32)*64 + chv1*8);  // shared
        bf16x8 p0 = kc ? pf01 : pf00;
        bf16x8 p1 = kc ? pf11 : pf10;
        oacc00 = __builtin_amdgcn_mfma_f32_32x32x16_bf16(vlo, p0, oacc00, 0,0,0);
        oacc01 = __builtin_amdgcn_mfma_f32_32x32x16_bf16(vhi, p0, oacc01, 0,0,0);
        oacc10 = __builtin_amdgcn_mfma_f32_32x32x16_bf16(vlo, p1, oacc10, 0,0,0);
        oacc11 = __builtin_amdgcn_mfma_f32_32x32x16_bf16(vhi, p1, oacc11, 0,0,0);
      }
    }
    __syncthreads();
  }

  lrun0 += __shfl_xor(lrun0, 32);
  lrun1 += __shfl_xor(lrun1, 32);
  float rinv0 = 1.0f / lrun0;
  float rinv1 = 1.0f / lrun1;
  size_t obase0 = ((size_t)b*N_ + qrow0)*C_ + h*D_;
  size_t obase1 = obase0 + (size_t)32*C_;
#pragma unroll
  for (int dh=0; dh<2; ++dh)
#pragma unroll
    for (int g=0; g<4; ++g) {
      int d = dh*32 + g*8 + hl*4;
      u16x4 o0, o1;
#pragma unroll
      for (int q=0;q<4;q++) {
        float v0 = (dh==0 ? oacc00[g*4+q] : oacc01[g*4+q]) * rinv0;
        float v1 = (dh==0 ? oacc10[g*4+q] : oacc11[g*4+q]) * rinv1;
        o0[q] = f2bf(v0);
        o1[q] = f2bf(v1);
      }
      *(u16x4*)(Ob + obase0 + d) = o0;
      *(u16x4*)(Ob + obase1 + d) = o1;
    }
}

// ---------------- output projection + residual fuse: Z = O@Wo^T + bo + 0.5*x1 (fp32) ----------------
__global__ __launch_bounds__(256) void out_gemm(
    const unsigned short* Ob, const unsigned short* Wo, const float* bo,
    const float* x1, float* Z)
{
  __shared__ unsigned short As[128*32];
  __shared__ unsigned short Bs[128*32];
  int rowBase = blockIdx.x*128, colBase = blockIdx.y*128;
  int tid = threadIdx.x, wave = tid>>6, lane = tid&63, quad = lane>>4, l16 = lane&15;
  int wm = wave>>1, wn = wave&1;
  f32x4 acc[4][4] = {};
  gemm_core(Ob, Wo, rowBase, colBase, acc, As, Bs);
#pragma unroll
  for (int i=0;i<4;i++)
#pragma unroll
    for (int j=0;j<4;j++) {
      int col = colBase + wn*64 + j*16 + l16;
      float bv_ = bo[col];
#pragma unroll
      for (int r=0;r<4;r++) {
        size_t m = rowBase + wm*64 + i*16 + quad*4 + r;
        Z[m*768 + col] = acc[i][j][r] + bv_ + 0.5f*x1[m*768 + col];
      }
    }
}

// ---------------- layernorm: one block per row ----------------
__global__ __launch_bounds__(256) void ln_kernel(const float* Z, const float* gam,
                                                 const float* bet, float* out)
{
  size_t row = blockIdx.x;
  int t = threadIdx.x;
  const float* z = Z + row*768;
  float v0 = z[t], v1 = z[t+256], v2 = z[t+512];
  float s = v0+v1+v2;
  float ss = v0*v0 + v1*v1 + v2*v2;
#pragma unroll
  for (int off=1; off<64; off<<=1) { s += __shfl_xor(s, off); ss += __shfl_xor(ss, off); }
  __shared__ float red[8];
  int wave = t>>6, lane = t&63;
  if (lane==0) { red[wave] = s; red[4+wave] = ss; }
  __syncthreads();
  float S = red[0]+red[1]+red[2]+red[3];
  float SS = red[4]+red[5]+red[6]+red[7];
  float mean = S * (1.0f/768.0f);
  float var = SS * (1.0f/768.0f) - mean*mean;
  float rstd = rsqrtf(var + 1e-5f);
  float* o = out + row*768;
  o[t]     = (v0-mean)*rstd*gam[t]     + bet[t];
  o[t+256] = (v1-mean)*rstd*gam[t+256] + bet[t+256];
  o[t+512] = (v2-mean)*rstd*gam[t+512] + bet[t+512];
}

extern "C" void kernel_launch(void* const* d_in, const int* in_sizes, int n_in,
                              void* d_out, int out_size, void* d_ws, size_t ws_size,
                              hipStream_t stream)
{
  const float* x1    = (const float*)d_in[0];
  const float* x2    = (const float*)d_in[1];
  const float* mask2 = (const float*)d_in[3];
  const float* Wq    = (const float*)d_in[4];
  const float* bq    = (const float*)d_in[5];
  const float* Wk    = (const float*)d_in[6];
  const float* bk    = (const float*)d_in[7];
  const float* Wv    = (const float*)d_in[8];
  const float* bv    = (const float*)d_in[9];
  const float* Wo    = (const float*)d_in[10];
  const float* bo    = (const float*)d_in[11];
  const float* temp  = (const float*)d_in[12];
  const float* gam   = (const float*)d_in[13];
  const float* bet   = (const float*)d_in[14];

  char* ws = (char*)d_ws;
  size_t off = 0;
  auto alloc = [&](size_t bytes) { void* p = ws + off; off += (bytes + 255) & ~255ull; return p; };
  const size_t XB = (size_t)NTOK * C_ * 2;   // 12582912
  const size_t WB = (size_t)C_ * C_ * 2;     // 1179648
  unsigned short* xb1 = (unsigned short*)alloc(XB);
  unsigned short* xb2 = (unsigned short*)alloc(XB);
  unsigned short* Wqb = (unsigned short*)alloc(WB);
  unsigned short* Wkb = (unsigned short*)alloc(WB);
  unsigned short* Wvb = (unsigned short*)alloc(WB);
  unsigned short* Wob = (unsigned short*)alloc(WB);
  unsigned short* Qb  = (unsigned short*)alloc(XB);
  unsigned short* Kb  = (unsigned short*)alloc(XB);
  unsigned short* Vt  = (unsigned short*)alloc(XB);  // V' directly in [B,H,D,N] slot-permuted
  unsigned short* Ob  = (unsigned short*)alloc(XB);
  float* u = (float*)alloc((size_t)NTOK * 4);        // per-key softmax weights
  // Z overlays xb1+xb2: both are dead after qkv_gemm, and Z is only written
  // by out_gemm, after attn.
  float* Z = (float*)xb1;   // 25165824 B overlays xb1+xb2

  cvt6<<<dim3(3072, 7), 256, 0, stream>>>(x1, x2, Wq, Wk, Wv, Wo,
                                          xb1, xb2, Wqb, Wkb, Wvb, Wob,
                                          mask2, temp, u,
                                          NTOK*C_, C_*C_);
  qkv_gemm<<<dim3(64, 6, 3), 256, 0, stream>>>(xb1, xb2, Wqb, Wkb, Wvb,
                                               bq, bk, bv, u, Qb, Kb, Vt);
  attn_kernel<<<dim3(384), 256, 0, stream>>>(Qb, Kb, Vt, u, Ob);
  out_gemm<<<dim3(64, 6), 256, 0, stream>>>(Ob, Wob, bo, x1, Z);
  ln_kernel<<<dim3(8192), 256, 0, stream>>>(Z, gam, bet, (float*)d_out);
}

// Round 8
// 291.839 us; speedup vs baseline: 1.0827x; 1.0684x over previous
//
#include <hip/hip_runtime.h>
#include <stdint.h>

#define B_ 4
#define N_ 2048
#define C_ 768
#define H_ 12
#define D_ 64
#define NTOK 8192   // B_*N_

typedef short bf16x8 __attribute__((ext_vector_type(8)));
typedef float f32x4 __attribute__((ext_vector_type(4)));
typedef float f32x16 __attribute__((ext_vector_type(16)));
typedef unsigned short ushort8 __attribute__((ext_vector_type(8)));
typedef unsigned short u16x4 __attribute__((ext_vector_type(4)));

__device__ __forceinline__ unsigned short f2bf(float f) {
  union { float f; unsigned u; } v; v.f = f;
  unsigned r = v.u + 0x7FFFu + ((v.u >> 16) & 1u);
  return (unsigned short)(r >> 16);
}

// async global->LDS, 16B per lane. lds base must be wave-uniform; HW adds lane*16.
__device__ __forceinline__ void load_lds16(const void* g, void* lds_base) {
  __builtin_amdgcn_global_load_lds(
      (const __attribute__((address_space(1))) unsigned int*)g,
      (__attribute__((address_space(3))) unsigned int*)(uint32_t)(uintptr_t)lds_base,
      16, 0, 0);
}

// Latin-square chunk swizzle: distinct within consecutive-8 AND stride-8 lane
// groups -> every 8-lane LDS service phase covers all 32 banks (row stride is
// 128B = 0 mod 32 banks, so plain key&7 left lanes 8 apart on the same quad).
__device__ __forceinline__ int fswz(int r) { return (r + (r >> 3)) & 7; }

// pack 8 non-negative floats -> bf16x8 via v_perm, truncating (softmax ratio
// cancels the tiny downward bias)
__device__ __forceinline__ bf16x8 pack8t(const float* p) {
  union { unsigned u[4]; bf16x8 v; } r;
#pragma unroll
  for (int j=0;j<4;j++) {
    union { float f; unsigned u; } a, b;
    a.f = p[2*j]; b.f = p[2*j+1];
    r.u[j] = __builtin_amdgcn_perm(b.u, a.u, 0x07060302u);
  }
  return r.v;
}

// ---------------- fp32 -> bf16 conversion (6 tensors) + u-table (y==6) ----------------
// u[b,m] = exp2(-mask2[b,m]*invT*log2e): per-key softmax bias factored out of exp.
__global__ __launch_bounds__(256) void cvt6(
    const float* s0, const float* s1, const float* s2, const float* s3,
    const float* s4, const float* s5,
    unsigned short* d0, unsigned short* d1, unsigned short* d2,
    unsigned short* d3, unsigned short* d4, unsigned short* d5,
    const float* mask2, const float* temp, float* u,
    int n01, int n25)
{
  int y = blockIdx.y;
  int i = (blockIdx.x*256 + threadIdx.x)*8;
  if (y == 6) {
    if (i >= NTOK) return;
    const float nsc = -1.4426950408889634f / temp[0];
    float4 f0 = *(const float4*)(mask2+i);
    float4 f1 = *(const float4*)(mask2+i+4);
    float4 o0, o1;
    o0.x = __builtin_amdgcn_exp2f(f0.x*nsc); o0.y = __builtin_amdgcn_exp2f(f0.y*nsc);
    o0.z = __builtin_amdgcn_exp2f(f0.z*nsc); o0.w = __builtin_amdgcn_exp2f(f0.w*nsc);
    o1.x = __builtin_amdgcn_exp2f(f1.x*nsc); o1.y = __builtin_amdgcn_exp2f(f1.y*nsc);
    o1.z = __builtin_amdgcn_exp2f(f1.z*nsc); o1.w = __builtin_amdgcn_exp2f(f1.w*nsc);
    *(float4*)(u+i) = o0;
    *(float4*)(u+i+4) = o1;
    return;
  }
  const float* s = (y==0)?s0:(y==1)?s1:(y==2)?s2:(y==3)?s3:(y==4)?s4:s5;
  unsigned short* d = (y==0)?d0:(y==1)?d1:(y==2)?d2:(y==3)?d3:(y==4)?d4:d5;
  int n = (y<2) ? n01 : n25;
  if (i >= n) return;
  float4 f0 = *(const float4*)(s+i);
  float4 f1 = *(const float4*)(s+i+4);
  ushort8 o;
  o[0]=f2bf(f0.x); o[1]=f2bf(f0.y); o[2]=f2bf(f0.z); o[3]=f2bf(f0.w);
  o[4]=f2bf(f1.x); o[5]=f2bf(f1.y); o[6]=f2bf(f1.z); o[7]=f2bf(f1.w);
  *(ushort8*)(d+i) = o;
}

// ---------------- shared GEMM core (R4 version): BK=32, 16.5KB LDS ----------------
__device__ __forceinline__ void gemm_core(const unsigned short* A, const unsigned short* W,
                                          int rowBase, int colBase, f32x4 (&acc)[4][4],
                                          unsigned short* As, unsigned short* Bs)
{
  int tid = threadIdx.x, wave = tid>>6, lane = tid&63, quad = lane>>4, l16 = lane&15;
  int wm = wave>>1, wn = wave&1;
  for (int k0 = 0; k0 < 768; k0 += 32) {
    __syncthreads();
#pragma unroll
    for (int p = 0; p < 2; ++p) {
      int c = p*256 + wave*64 + lane;
      load_lds16(A + (size_t)(rowBase + (c>>2))*768 + k0 + (c&3)*8,
                 As + (size_t)(p*256 + wave*64)*8);
      load_lds16(W + (size_t)(colBase + (c>>2))*768 + k0 + (c&3)*8,
                 Bs + (size_t)(p*256 + wave*64)*8);
    }
    __syncthreads();
    bf16x8 af[4], bw[4];
#pragma unroll
    for (int i=0;i<4;i++) af[i] = *(const bf16x8*)(As + (wm*64 + i*16 + l16)*32 + quad*8);
#pragma unroll
    for (int j=0;j<4;j++) bw[j] = *(const bf16x8*)(Bs + (wn*64 + j*16 + l16)*32 + quad*8);
#pragma unroll
    for (int i=0;i<4;i++)
#pragma unroll
      for (int j=0;j<4;j++)
        acc[i][j] = __builtin_amdgcn_mfma_f32_16x16x32_bf16(af[i], bw[j], acc[i][j], 0,0,0);
  }
}

// ---------------- QKV projection ----------------
// Q output scaled by SCL=0.125*log2e (exp2 arg needs no fma in attn).
// V output: transposed+slot-permuted [B,H,D,N], PRE-MULTIPLIED by u[key]
// (per-key softmax bias folded into V -> attn's PV needs no bias at all).
__global__ __launch_bounds__(256) void qkv_gemm(
    const unsigned short* xb1, const unsigned short* xb2,
    const unsigned short* Wq, const unsigned short* Wk, const unsigned short* Wv,
    const float* bq, const float* bk, const float* bv, const float* u,
    unsigned short* Qb, unsigned short* Kb, unsigned short* Vt)
{
  __shared__ unsigned short As[128*32];
  __shared__ unsigned short Bs[128*32];
  int z = blockIdx.z;
  const unsigned short* A = (z==0) ? xb1 : xb2;
  const unsigned short* W = (z==0) ? Wq : (z==1) ? Wk : Wv;
  const float* bias       = (z==0) ? bq : (z==1) ? bk : bv;
  int rowBase = blockIdx.x*128, colBase = blockIdx.y*128;
  int tid = threadIdx.x, wave = tid>>6, lane = tid&63, quad = lane>>4, l16 = lane&15;
  int wm = wave>>1, wn = wave&1;
  f32x4 acc[4][4] = {};
  gemm_core(A, W, rowBase, colBase, acc, As, Bs);
  if (z == 2) {
    // V': transposed write [B,H,D,N] with key->slot permutation, scaled by u[key]
#pragma unroll
    for (int i=0;i<4;i++) {
      int m0 = rowBase + wm*64 + i*16 + quad*4;     // global token row (b*2048+n)
      float4 uv = *(const float4*)(u + m0);          // u for keys m0..m0+3
      int b = m0 >> 11, n0 = m0 & 2047;
      int slotbase = (n0 & ~63) | (i*16) | ((quad&1)<<3) | ((quad>>1)<<2);
#pragma unroll
      for (int j=0;j<4;j++) {
        int col = colBase + wn*64 + j*16 + l16;
        float bv_ = bias[col];
        int h = col >> 6, d = col & 63;
        u16x4 o;
        o[0] = f2bf((acc[i][j][0] + bv_) * uv.x);
        o[1] = f2bf((acc[i][j][1] + bv_) * uv.y);
        o[2] = f2bf((acc[i][j][2] + bv_) * uv.z);
        o[3] = f2bf((acc[i][j][3] + bv_) * uv.w);
        *(u16x4*)(Vt + (((size_t)b*H_ + h)*D_ + d)*(size_t)N_ + slotbase) = o;
      }
    }
  } else {
    unsigned short* out = (z==0) ? Qb : Kb;
    float qs = (z==0) ? 0.18033688011112042f : 1.0f;  // 0.125*log2e for Q
#pragma unroll
    for (int i=0;i<4;i++)
#pragma unroll
      for (int j=0;j<4;j++) {
        int col = colBase + wn*64 + j*16 + l16;
        float bv_ = bias[col];
        int h = col >> 6, d = col & 63;
#pragma unroll
        for (int r=0;r<4;r++) {
          int m = rowBase + wm*64 + i*16 + quad*4 + r;
          int b = m >> 11, n = m & 2047;
          out[(((size_t)b*H_ + h)*N_ + n)*D_ + d] = f2bf((acc[i][j][r] + bv_) * qs);
        }
      }
  }
}

// stage one 64-tile of K ([key][d]) and V'^T ([d][slot]) via pure async loads,
// with source-side Latin chunk swizzle for conflict-free b128 fragment reads.
__device__ __forceinline__ void attn_stage(const unsigned short* Kb, const unsigned short* Vtg,
                                           size_t bh, int kt, int tid, int wave,
                                           unsigned short* KsBuf, unsigned short* VsBuf)
{
#pragma unroll
  for (int p=0;p<2;p++) {
    int idx = p*256 + tid;
    int key = idx >> 3, c = idx & 7;
    load_lds16(Kb + (bh*N_ + (size_t)kt*64 + key)*D_ + (c ^ fswz(key))*8,
               KsBuf + (size_t)(p*256 + wave*64)*8);
  }
#pragma unroll
  for (int p=0;p<2;p++) {
    int idx = p*256 + tid;
    int d = idx >> 3, c = idx & 7;
    load_lds16(Vtg + (bh*D_ + d)*(size_t)N_ + kt*64 + (c ^ fswz(d))*8,
               VsBuf + (size_t)(p*256 + wave*64)*8);
  }
}

// ---------------- flash attention (R13: R4 structure + Latin swizzle) ----------------
__global__ __launch_bounds__(256) void attn_kernel(
    const unsigned short* Qb, const unsigned short* Kb, const unsigned short* Vtg,
    const float* u, unsigned short* Ob)
{
  __shared__ unsigned short Ks[2][64*64];  // [buf][key][chunk Latin-swizzled]
  __shared__ unsigned short Vs[2][64*64];  // [buf][d][chunk Latin-swizzled]
  __shared__ float us[N_];                 // per-key weights for this b (8 KB)
  int bx = blockIdx.x;                     // 0..767
  int xcd = bx & 7, slot = bx >> 3;        // 96 slots per xcd
  int bh_i = xcd*6 + (slot >> 4);          // 0..47
  int qt = slot & 15;
  int b = bh_i / H_, h = bh_i - b*H_;
  int tid = threadIdx.x, wave = tid>>6, lane = tid&63;
  int l32 = lane & 31, hl = lane >> 5;
  size_t bh = (size_t)bh_i;
  int qrow = qt*128 + wave*32 + l32;
  int fsb = l32 + (l32 >> 3);              // fswz base: fswz(s*32+l32) = (fsb+4*s)&7

  // copy u[b,:] into LDS (lgkmcnt path, decoupled from staging vmcnt)
#pragma unroll
  for (int r=0;r<2;r++) {
    int i = (r*256 + tid)*4;
    *(float4*)(us+i) = *(const float4*)(u + (size_t)b*N_ + i);
  }

  bf16x8 qf[4];
  const unsigned short* Qp = Qb + (bh*N_ + qrow)*D_;
#pragma unroll
  for (int i=0;i<4;i++) qf[i] = *(const bf16x8*)(Qp + i*16 + hl*8);

  float lrun = 0.f;
  f32x16 oacc0 = {}, oacc1 = {};

  attn_stage(Kb, Vtg, bh, 0, tid, wave, Ks[0], Vs[0]);
  __syncthreads();   // also covers us writes

  for (int kt = 0; kt < N_/64; ++kt) {
    int cur = kt & 1;
    if (kt+1 < N_/64)
      attn_stage(Kb, Vtg, bh, kt+1, tid, wave, Ks[cur^1], Vs[cur^1]);
    const unsigned short* Kc = Ks[cur];
    const unsigned short* Vc = Vs[cur];
#pragma unroll
    for (int sub=0; sub<2; ++sub) {
      f32x16 sa = {};
#pragma unroll
      for (int i=0;i<4;i++) {
        int ch = (2*i + hl) ^ ((fsb + 4*sub) & 7);
        bf16x8 kf = *(const bf16x8*)(Kc + (sub*32 + l32)*64 + ch*8);
        sa = __builtin_amdgcn_mfma_f32_32x32x16_bf16(kf, qf[i], sa, 0,0,0);
      }
      float pv[16];
      float la[4];
#pragma unroll
      for (int g=0; g<4; ++g) {
        float4 uv = *(const float4*)(us + kt*64 + sub*32 + g*8 + hl*4);
        float p0 = __builtin_amdgcn_exp2f(sa[g*4+0]);
        float p1 = __builtin_amdgcn_exp2f(sa[g*4+1]);
        float p2 = __builtin_amdgcn_exp2f(sa[g*4+2]);
        float p3 = __builtin_amdgcn_exp2f(sa[g*4+3]);
        pv[g*4+0]=p0; pv[g*4+1]=p1; pv[g*4+2]=p2; pv[g*4+3]=p3;
        la[g] = fmaf(p0, uv.x, fmaf(p1, uv.y, fmaf(p2, uv.z, p3*uv.w)));
      }
      lrun += (la[0]+la[1]) + (la[2]+la[3]);
      bf16x8 pf0 = pack8t(pv);
      bf16x8 pf1 = pack8t(pv+8);
#pragma unroll
      for (int kc=0;kc<2;kc++) {
        bf16x8 pf = kc ? pf1 : pf0;
        int m = sub*2 + kc;
        int chv = (2*m + hl) ^ (fsb & 7);
        oacc0 = __builtin_amdgcn_mfma_f32_32x32x16_bf16(
                  *(const bf16x8*)(Vc + l32*64 + chv*8), pf, oacc0, 0,0,0);
        int chv1 = (2*m + hl) ^ ((fsb + 4) & 7);
        oacc1 = __builtin_amdgcn_mfma_f32_32x32x16_bf16(
                  *(const bf16x8*)(Vc + (32+l32)*64 + chv1*8), pf, oacc1, 0,0,0);
      }
    }
    __syncthreads();
  }

  lrun += __shfl_xor(lrun, 32);
  float rinv = 1.0f / lrun;
  size_t obase = ((size_t)b*N_ + qrow)*C_ + h*D_;
#pragma unroll
  for (int dh=0; dh<2; ++dh)
#pragma unroll
    for (int g=0; g<4; ++g) {
      int d = dh*32 + g*8 + hl*4;
      u16x4 o;
#pragma unroll
      for (int q=0;q<4;q++) {
        float val = (dh==0 ? oacc0[g*4+q] : oacc1[g*4+q]) * rinv;
        o[q] = f2bf(val);
      }
      *(u16x4*)(Ob + obase + d) = o;
    }
}

// ---------------- output projection + residual fuse: Z = O@Wo^T + bo + 0.5*x1 (fp32) ----------------
__global__ __launch_bounds__(256) void out_gemm(
    const unsigned short* Ob, const unsigned short* Wo, const float* bo,
    const float* x1, float* Z)
{
  __shared__ unsigned short As[128*32];
  __shared__ unsigned short Bs[128*32];
  int rowBase = blockIdx.x*128, colBase = blockIdx.y*128;
  int tid = threadIdx.x, wave = tid>>6, lane = tid&63, quad = lane>>4, l16 = lane&15;
  int wm = wave>>1, wn = wave&1;
  f32x4 acc[4][4] = {};
  gemm_core(Ob, Wo, rowBase, colBase, acc, As, Bs);
#pragma unroll
  for (int i=0;i<4;i++)
#pragma unroll
    for (int j=0;j<4;j++) {
      int col = colBase + wn*64 + j*16 + l16;
      float bv_ = bo[col];
#pragma unroll
      for (int r=0;r<4;r++) {
        size_t m = rowBase + wm*64 + i*16 + quad*4 + r;
        Z[m*768 + col] = acc[i][j][r] + bv_ + 0.5f*x1[m*768 + col];
      }
    }
}

// ---------------- layernorm: one block per row ----------------
__global__ __launch_bounds__(256) void ln_kernel(const float* Z, const float* gam,
                                                 const float* bet, float* out)
{
  size_t row = blockIdx.x;
  int t = threadIdx.x;
  const float* z = Z + row*768;
  float v0 = z[t], v1 = z[t+256], v2 = z[t+512];
  float s = v0+v1+v2;
  float ss = v0*v0 + v1*v1 + v2*v2;
#pragma unroll
  for (int off=1; off<64; off<<=1) { s += __shfl_xor(s, off); ss += __shfl_xor(ss, off); }
  __shared__ float red[8];
  int wave = t>>6, lane = t&63;
  if (lane==0) { red[wave] = s; red[4+wave] = ss; }
  __syncthreads();
  float S = red[0]+red[1]+red[2]+red[3];
  float SS = red[4]+red[5]+red[6]+red[7];
  float mean = S * (1.0f/768.0f);
  float var = SS * (1.0f/768.0f) - mean*mean;
  float rstd = rsqrtf(var + 1e-5f);
  float* o = out + row*768;
  o[t]     = (v0-mean)*rstd*gam[t]     + bet[t];
  o[t+256] = (v1-mean)*rstd*gam[t+256] + bet[t+256];
  o[t+512] = (v2-mean)*rstd*gam[t+512] + bet[t+512];
}

extern "C" void kernel_launch(void* const* d_in, const int* in_sizes, int n_in,
                              void* d_out, int out_size, void* d_ws, size_t ws_size,
                              hipStream_t stream)
{
  const float* x1    = (const float*)d_in[0];
  const float* x2    = (const float*)d_in[1];
  const float* mask2 = (const float*)d_in[3];
  const float* Wq    = (const float*)d_in[4];
  const float* bq    = (const float*)d_in[5];
  const float* Wk    = (const float*)d_in[6];
  const float* bk    = (const float*)d_in[7];
  const float* Wv    = (const float*)d_in[8];
  const float* bv    = (const float*)d_in[9];
  const float* Wo    = (const float*)d_in[10];
  const float* bo    = (const float*)d_in[11];
  const float* temp  = (const float*)d_in[12];
  const float* gam   = (const float*)d_in[13];
  const float* bet   = (const float*)d_in[14];

  char* ws = (char*)d_ws;
  size_t off = 0;
  auto alloc = [&](size_t bytes) { void* p = ws + off; off += (bytes + 255) & ~255ull; return p; };
  const size_t XB = (size_t)NTOK * C_ * 2;   // 12582912
  const size_t WB = (size_t)C_ * C_ * 2;     // 1179648
  unsigned short* xb1 = (unsigned short*)alloc(XB);
  unsigned short* xb2 = (unsigned short*)alloc(XB);
  unsigned short* Wqb = (unsigned short*)alloc(WB);
  unsigned short* Wkb = (unsigned short*)alloc(WB);
  unsigned short* Wvb = (unsigned short*)alloc(WB);
  unsigned short* Wob = (unsigned short*)alloc(WB);
  unsigned short* Qb  = (unsigned short*)alloc(XB);
  unsigned short* Kb  = (unsigned short*)alloc(XB);
  unsigned short* Vt  = (unsigned short*)alloc(XB);  // V' directly in [B,H,D,N] slot-permuted
  unsigned short* Ob  = (unsigned short*)alloc(XB);
  float* u = (float*)alloc((size_t)NTOK * 4);        // per-key softmax weights
  // Z overlays xb1+xb2: both are dead after qkv_gemm, and Z is only written
  // by out_gemm, after attn.
  float* Z = (float*)xb1;   // 25165824 B overlays xb1+xb2

  cvt6<<<dim3(3072, 7), 256, 0, stream>>>(x1, x2, Wq, Wk, Wv, Wo,
                                          xb1, xb2, Wqb, Wkb, Wvb, Wob,
                                          mask2, temp, u,
                                          NTOK*C_, C_*C_);
  qkv_gemm<<<dim3(64, 6, 3), 256, 0, stream>>>(xb1, xb2, Wqb, Wkb, Wvb,
                                               bq, bk, bv, u, Qb, Kb, Vt);
  attn_kernel<<<dim3(768), 256, 0, stream>>>(Qb, Kb, Vt, u, Ob);
  out_gemm<<<dim3(64, 6), 256, 0, stream>>>(Ob, Wob, bo, x1, Z);
  ln_kernel<<<dim3(8192), 256, 0, stream>>>(Z, gam, bet, (float*)d_out);
}